// Round 10
// baseline (214.833 us; speedup 1.0000x reference)
//
#include <hip/hip_runtime.h>

#define N_NODES 50000
#define N_EDGES 800000
#define IN_DIM 16
#define OUT_DIM 16
#define N_RELS 90
#define N_BASES 30

#define CAP 64            // 8B entries -> 512B/node row
#define RLDS_STRIDE 132   // 16 rows x 8 cols + 4 pad: +4 bank rotation per rel

#define PREP_BLOCKS 91   // 91*256 = 23296 >= 23088
#define DOTS_BLOCKS 196  // 196*256 = 50176 >= 50000
#define ZERO_BLOCKS 196
#define HZ_BLOCKS 782    // 782*256 float4 >= 200000 float4 (zero hout)

#define ROUTE_BLOCKS 3125    // 1 edge/thread, 256/block
#define RNODES_PER_BLK 64    // reduce: 1024 thr / 16 lanes-per-node
#define REDUCE_PAIRS 782     // 782*64 = 50048 >= 50000; grid = 2x (col halves)

__device__ __forceinline__ float4 shfl_xor4(float4 v, int m) {
    float4 r;
    r.x = __shfl_xor(v.x, m); r.y = __shfl_xor(v.y, m);
    r.z = __shfl_xor(v.z, m); r.w = __shfl_xor(v.w, m);
    return r;
}

// ---------------------------------------------------------------------------
// Setup: [0,91) prep Wrel+avec; [91,287) node dots s1/s3; [287,483) zero cnt;
// [483,1265) zero hout.
// ---------------------------------------------------------------------------
__global__ __launch_bounds__(256) void setup_kernel(
    const float* __restrict__ Ws,
    const float* __restrict__ Wa,
    const float* __restrict__ weight,
    const float* __restrict__ w_comp,
    const float* __restrict__ h,
    float* __restrict__ Wrel,
    float* __restrict__ avec,
    float* __restrict__ s1,
    float* __restrict__ s3,
    int* __restrict__ cnt,
    float* __restrict__ hout)
{
    int b = blockIdx.x;
    if (b < PREP_BLOCKS) {
        int f = b * 256 + threadIdx.x;
        if (f < N_RELS * IN_DIM * OUT_DIM) {
            int a   = f / (N_RELS * OUT_DIM);
            int rem = f % (N_RELS * OUT_DIM);
            int r   = rem / OUT_DIM;
            int o   = rem % OUT_DIM;
            float acc = 0.f;
            #pragma unroll
            for (int bb = 0; bb < N_BASES; ++bb)
                acc += w_comp[r * N_BASES + bb] * weight[a * (N_BASES * OUT_DIM) + bb * OUT_DIM + o];
            Wrel[f] = acc;
        } else if (f < N_RELS * IN_DIM * OUT_DIM + 48) {
            int g = f - N_RELS * IN_DIM * OUT_DIM;
            int k = g / IN_DIM;
            int i = g % IN_DIM;
            float acc = 0.f;
            #pragma unroll
            for (int o = 0; o < OUT_DIM; ++o)
                acc += Wa[k * OUT_DIM + o] * Ws[o * IN_DIM + i];
            avec[g] = acc;
        }
    } else if (b < PREP_BLOCKS + DOTS_BLOCKS) {
        __shared__ float la[48];
        if (threadIdx.x < 48) {
            int k = threadIdx.x / IN_DIM;
            int i = threadIdx.x % IN_DIM;
            float acc = 0.f;
            #pragma unroll
            for (int o = 0; o < OUT_DIM; ++o)
                acc += Wa[k * OUT_DIM + o] * Ws[o * IN_DIM + i];
            la[threadIdx.x] = acc;
        }
        __syncthreads();
        int n = (b - PREP_BLOCKS) * 256 + threadIdx.x;
        if (n >= N_NODES) return;
        const float4* p = (const float4*)(h + (size_t)n * IN_DIM);
        float d1 = 0.f, d3 = 0.f;
        #pragma unroll
        for (int i = 0; i < 4; ++i) {
            float4 v = p[i];
            d1 += v.x * la[4*i+0] + v.y * la[4*i+1] + v.z * la[4*i+2] + v.w * la[4*i+3];
            d3 += v.x * la[32+4*i+0] + v.y * la[32+4*i+1] + v.z * la[32+4*i+2] + v.w * la[32+4*i+3];
        }
        s1[n] = d1;
        s3[n] = d3;
    } else if (b < PREP_BLOCKS + DOTS_BLOCKS + ZERO_BLOCKS) {
        int n = (b - PREP_BLOCKS - DOTS_BLOCKS) * 256 + threadIdx.x;
        if (n < N_NODES) cnt[n] = 0;
    } else {
        int idx = (b - PREP_BLOCKS - DOTS_BLOCKS - ZERO_BLOCKS) * 256 + threadIdx.x;
        if (idx < N_NODES * OUT_DIM / 4) {
            float4 z = {0.f, 0.f, 0.f, 0.f};
            ((float4*)hout)[idx] = z;
        }
    }
}

// ---------------------------------------------------------------------------
// Route: 1 edge/thread, contiguous (coalesced idx + he stream). Only TWO
// random memory ops per edge: the cnt atomic and the 8B entry store.
// Entry carries pd = he[e] . a_edge; score finalized in reduce.
// ---------------------------------------------------------------------------
__global__ __launch_bounds__(256) void route_kernel(
    const float* __restrict__ h,
    const float* __restrict__ he,
    const int* __restrict__ src,
    const int* __restrict__ dst,
    const int* __restrict__ rel,
    const float* __restrict__ Wrel,
    const float* __restrict__ avec,
    const float* __restrict__ s1,
    const float* __restrict__ s3,
    int* __restrict__ cnt,
    uint2* __restrict__ bucket,
    float* __restrict__ hout)
{
    int e = blockIdx.x * 256 + threadIdx.x;
    if (e >= N_EDGES) return;
    int s = src[e], d = dst[e], r = rel[e];

    const float4* hep = (const float4*)(he + (size_t)e * IN_DIM);
    const float4* ap  = (const float4*)(avec + 16);
    float pd = 0.f;
    #pragma unroll
    for (int i = 0; i < 4; ++i) {
        float4 v = hep[i];
        float4 a = ap[i];
        pd += v.x * a.x + v.y * a.y + v.z * a.z + v.w * a.w;
    }

    int slot = atomicAdd(&cnt[d], 1);
    if (slot < CAP) {
        uint2 ent;
        ent.x = ((unsigned)r << 16) | (unsigned)s;   // s < 50000 < 2^16, r < 90
        ent.y = __float_as_uint(pd);
        bucket[(size_t)d * CAP + slot] = ent;
    } else {
        // rare/never: full message from global Wrel (L2-hot), full score here
        float score = s1[s] + s3[d] + pd;
        float hs[16];
        const float4* hp = (const float4*)(h + (size_t)s * IN_DIM);
        #pragma unroll
        for (int i = 0; i < 4; ++i) {
            float4 v = hp[i];
            hs[4*i+0] = v.x; hs[4*i+1] = v.y; hs[4*i+2] = v.z; hs[4*i+3] = v.w;
        }
        const float* W = Wrel + (size_t)r * 256;
        float* outp = hout + (size_t)d * OUT_DIM;
        #pragma unroll
        for (int o = 0; o < OUT_DIM; ++o) {
            float acc = 0.f;
            #pragma unroll
            for (int i = 0; i < IN_DIM; ++i) acc += hs[i] * W[i * OUT_DIM + o];
            atomicAdd(outp + o, acc * score);
        }
    }
}

// ---------------------------------------------------------------------------
// Reduce+BMM, COLUMN-SPLIT: grid = 2x782; c = blockIdx&1 selects output cols
// c*8..c*8+7, node tile = blockIdx>>1. Each block stages 90 rels x 16 rows x
// 8 cols = 47.5KB LDS -> 2 blocks/CU = 32 waves/CU. NO work duplication on
// the entry scan: every entry is consumed by both pair blocks (half the
// output cols each), so total FMA = round-6 exactly. Outputs are disjoint
// col-halves -> plain float2 stores, no atomics (round-9's 25MB atomic
// write regression reverts). Only duplication: 8B entry broadcasts + h/s1
// gathers (2nd reader L3-absorbed). Datapath: same XOR-row quad transpose
// (q in 0..3 distributes all 16 h rows), W reads are ds_read_b64 (float2,
// cols 2q..2q+1 of the half). Cross-stream butterfly (xor 4,8).
// ---------------------------------------------------------------------------
__global__ __launch_bounds__(1024) void reduce_bmm_kernel(
    const float* __restrict__ h,
    const float* __restrict__ Wrel,
    const float* __restrict__ s1,
    const float* __restrict__ s3,
    const uint2* __restrict__ bucket,
    const int* __restrict__ cnt,
    float* __restrict__ hout)
{
    extern __shared__ float lw[];   // [N_RELS * RLDS_STRIDE] = 47.5KB
    const unsigned c = blockIdx.x & 1;

    // stage cols c*8..c*8+7 of every rel: rel r, row, half4 in {0,1}
    for (int j = threadIdx.x; j < N_RELS * 32; j += 1024) {
        int r   = j >> 5;
        int rem = j & 31;
        int row = rem >> 1;
        int h4  = rem & 1;
        float4 v = ((const float4*)Wrel)[r * 64 + row * 4 + c * 2 + h4];
        *(float4*)(lw + r * RLDS_STRIDE + row * 8 + h4 * 4) = v;
    }
    __syncthreads();

    const int l = threadIdx.x & 15;
    const int q = l & 3;
    const int p = l >> 2;               // 0..3: entry stream
    const int n = (blockIdx.x >> 1) * RNODES_PER_BLK + (threadIdx.x >> 4);
    if (n >= N_NODES) return;

    int deg = cnt[n];
    int m = deg > CAP ? CAP : deg;
    const uint2* ep = bucket + (size_t)n * CAP;
    float s3n = s3[n];
    float2 acc = {0.f, 0.f};

    for (int j0 = 0; j0 < m; j0 += 8) {
        uint2 ent[2];
        float4 hq[2];
        float s1v[2];
        bool val[2];

        // [1] entry loads (4 q-lanes share addr -> broadcast)
        #pragma unroll
        for (int k = 0; k < 2; ++k) {
            int j = j0 + p * 2 + k;
            val[k] = (j < m);
            ent[k] = ep[val[k] ? j : 0];
        }

        // [2] gathers: h[src] 16B/lane + s1[src] (quad-broadcast)
        #pragma unroll
        for (int k = 0; k < 2; ++k) {
            int sidx = ent[k].x & 0xFFFF;
            hq[k]  = *(const float4*)(h + (size_t)sidx * IN_DIM + q * 4);
            s1v[k] = s1[sidx];
        }

        // [3] process (val[k] uniform across the 4 q-lanes of (n,p))
        #pragma unroll
        for (int k = 0; k < 2; ++k) {
            if (!val[k]) continue;
            unsigned rr = ent[k].x >> 16;
            float score = s1v[k] + s3n + __uint_as_float(ent[k].y);
            float4 hx = hq[k];
            hx.x *= score; hx.y *= score; hx.z *= score; hx.w *= score;

            const float* wb = lw + (size_t)rr * RLDS_STRIDE + 2 * q;
            #pragma unroll
            for (int mm = 0; mm < 4; ++mm) {
                float4 vm = (mm == 0) ? hx : shfl_xor4(hx, mm);
                const float* wrow = wb + (((unsigned)(q ^ mm)) << 5);
                float2 w0 = *(const float2*)(wrow +  0);
                float2 w1 = *(const float2*)(wrow +  8);
                float2 w2 = *(const float2*)(wrow + 16);
                float2 w3 = *(const float2*)(wrow + 24);
                acc.x += vm.x*w0.x + vm.y*w1.x + vm.z*w2.x + vm.w*w3.x;
                acc.y += vm.x*w0.y + vm.y*w1.y + vm.z*w2.y + vm.w*w3.y;
            }
        }
    }

    // cross-stream butterfly (within the node's 16 lanes)
    acc.x += __shfl_xor(acc.x, 4); acc.y += __shfl_xor(acc.y, 4);
    acc.x += __shfl_xor(acc.x, 8); acc.y += __shfl_xor(acc.y, 8);

    if (p == 0) {
        float* outp = hout + (size_t)n * OUT_DIM + c * 8 + q * 2;
        if (deg <= CAP) {
            *(float2*)outp = acc;    // disjoint col-halves: no race
        } else {
            atomicAdd(outp + 0, acc.x);
            atomicAdd(outp + 1, acc.y);
        }
    }
}

// ===========================================================================
// Fallback (ws too small): direct atomic scatter (known-correct).
// ===========================================================================
__global__ __launch_bounds__(256) void prep_kernel(
    const float* __restrict__ Ws, const float* __restrict__ Wa,
    const float* __restrict__ weight, const float* __restrict__ w_comp,
    float* __restrict__ Wrel, float* __restrict__ avec)
{
    int f = blockIdx.x * blockDim.x + threadIdx.x;
    if (f < N_RELS * IN_DIM * OUT_DIM) {
        int a   = f / (N_RELS * OUT_DIM);
        int rem = f % (N_RELS * OUT_DIM);
        int r   = rem / OUT_DIM;
        int o   = rem % OUT_DIM;
        float acc = 0.f;
        #pragma unroll
        for (int b = 0; b < N_BASES; ++b)
            acc += w_comp[r * N_BASES + b] * weight[a * (N_BASES * OUT_DIM) + b * OUT_DIM + o];
        Wrel[f] = acc;
    } else if (f < N_RELS * IN_DIM * OUT_DIM + 48) {
        int g = f - N_RELS * IN_DIM * OUT_DIM;
        int k = g / IN_DIM;
        int i = g % IN_DIM;
        float acc = 0.f;
        #pragma unroll
        for (int o = 0; o < OUT_DIM; ++o)
            acc += Wa[k * OUT_DIM + o] * Ws[o * IN_DIM + i];
        avec[g] = acc;
    }
}

__global__ __launch_bounds__(256) void edge_atomic_kernel(
    const float* __restrict__ h,
    const float* __restrict__ he,
    const int* __restrict__ src,
    const int* __restrict__ dst,
    const int* __restrict__ rel,
    const float* __restrict__ Wrel,
    const float* __restrict__ avec,
    float* __restrict__ hout)
{
    int e = blockIdx.x * blockDim.x + threadIdx.x;
    if (e >= N_EDGES) return;
    int s = src[e], d = dst[e], r = rel[e];
    float hs[IN_DIM];
    const float4* p = (const float4*)(h + (size_t)s * IN_DIM);
    #pragma unroll
    for (int i = 0; i < 4; ++i) {
        float4 v = p[i];
        hs[4*i+0] = v.x; hs[4*i+1] = v.y; hs[4*i+2] = v.z; hs[4*i+3] = v.w;
    }
    float score = 0.f;
    #pragma unroll
    for (int i = 0; i < IN_DIM; ++i) score += hs[i] * avec[i];
    const float4* qe = (const float4*)(he + (size_t)e * IN_DIM);
    #pragma unroll
    for (int i = 0; i < 4; ++i) {
        float4 v = qe[i];
        score += v.x * avec[16+4*i] + v.y * avec[17+4*i] + v.z * avec[18+4*i] + v.w * avec[19+4*i];
    }
    const float4* pd = (const float4*)(h + (size_t)d * IN_DIM);
    #pragma unroll
    for (int i = 0; i < 4; ++i) {
        float4 v = pd[i];
        score += v.x * avec[32+4*i] + v.y * avec[33+4*i] + v.z * avec[34+4*i] + v.w * avec[35+4*i];
    }
    float acc[OUT_DIM];
    #pragma unroll
    for (int o = 0; o < OUT_DIM; ++o) acc[o] = 0.f;
    const float* W = Wrel + (size_t)r * 256;
    #pragma unroll
    for (int i = 0; i < IN_DIM; ++i) {
        float hv = hs[i];
        #pragma unroll
        for (int o = 0; o < OUT_DIM; ++o) acc[o] += hv * W[i * OUT_DIM + o];
    }
    float* outp = hout + (size_t)d * OUT_DIM;
    #pragma unroll
    for (int o = 0; o < OUT_DIM; ++o) atomicAdd(outp + o, acc[o] * score);
}

extern "C" void kernel_launch(void* const* d_in, const int* in_sizes, int n_in,
                              void* d_out, int out_size, void* d_ws, size_t ws_size,
                              hipStream_t stream) {
    const float* h      = (const float*)d_in[0];
    const float* he     = (const float*)d_in[1];
    const float* Ws     = (const float*)d_in[2];
    const float* Wa     = (const float*)d_in[3];
    const float* weight = (const float*)d_in[4];
    const float* w_comp = (const float*)d_in[5];
    const int*   src    = (const int*)d_in[6];
    const int*   dst    = (const int*)d_in[7];
    const int*   rel    = (const int*)d_in[8];
    float* hout = (float*)d_out;

    // ws layout (float offsets)
    const size_t OFF_WREL   = 0;         // 23040 f
    const size_t OFF_AVEC   = 23040;     // 48 f (+16 pad)
    const size_t OFF_S1     = 23104;     // 50000 f
    const size_t OFF_S3     = 73104;     // 50000 f
    const size_t OFF_CNT    = 123104;    // 50000 i
    const size_t OFF_BUCKET = 173104;    // N*CAP uint2 (8B aligned)
    const size_t NEED_BUCKET = OFF_BUCKET * 4 + (size_t)N_NODES * CAP * sizeof(uint2);

    float* wsf  = (float*)d_ws;
    float* Wrel = wsf + OFF_WREL;
    float* avec = wsf + OFF_AVEC;
    float* s1   = wsf + OFF_S1;
    float* s3   = wsf + OFF_S3;
    int* cnt    = (int*)(wsf + OFF_CNT);

    if (ws_size >= NEED_BUCKET) {
        uint2* bucket = (uint2*)(wsf + OFF_BUCKET);

        setup_kernel<<<PREP_BLOCKS + DOTS_BLOCKS + ZERO_BLOCKS + HZ_BLOCKS, 256, 0, stream>>>(
            Ws, Wa, weight, w_comp, h, Wrel, avec, s1, s3, cnt, hout);
        route_kernel<<<ROUTE_BLOCKS, 256, 0, stream>>>(
            h, he, src, dst, rel, Wrel, avec, s1, s3, cnt, bucket, hout);
        reduce_bmm_kernel<<<2 * REDUCE_PAIRS, 1024,
                            N_RELS * RLDS_STRIDE * sizeof(float), stream>>>(
            h, Wrel, s1, s3, bucket, cnt, hout);
    } else {
        hipMemsetAsync(d_out, 0, (size_t)out_size * sizeof(float), stream);
        int total = N_RELS * IN_DIM * OUT_DIM + 48;
        prep_kernel<<<(total + 255) / 256, 256, 0, stream>>>(Ws, Wa, weight, w_comp, Wrel, avec);
        edge_atomic_kernel<<<(N_EDGES + 255) / 256, 256, 0, stream>>>(
            h, he, src, dst, rel, Wrel, avec, hout);
    }
}

// Round 11
// 191.439 us; speedup vs baseline: 1.1222x; 1.1222x over previous
//
#include <hip/hip_runtime.h>

#define N_NODES 50000
#define N_EDGES 800000
#define IN_DIM 16
#define OUT_DIM 16
#define N_RELS 90
#define N_BASES 30

#define CAP 64          // 8B entries -> 512B/node row
#define LDS_STRIDE 260  // 256 + 4 pad; bank rotation +4/rel, 16B aligned
#define SPILL_MAX 4096  // overflow entries (deg>CAP); statistically never hit

#define CNT_BLOCKS 196       // pre: 196*256 >= 50000
#define EDGE2_BLOCKS 1563    // route: 1563*512 >= 800000 (2 edges/thread)
#define DOTS_BLOCKS 196      // fused into route grid
#define WPREP_BLOCKS 91      // fused into route grid: 91*256 >= 23040
#define REDUCE_BLOCKS 256    // persistent: 1 block/CU, 64-node tiles

__device__ __forceinline__ float4 shfl_xor4(float4 v, int m) {
    float4 r;
    r.x = __shfl_xor(v.x, m); r.y = __shfl_xor(v.y, m);
    r.z = __shfl_xor(v.z, m); r.w = __shfl_xor(v.w, m);
    return r;
}

// ---------------------------------------------------------------------------
// Pre: zero cnt + spill counter, compute avec (48 dots). Tiny (~197 blocks).
// Everything else (Wrel, s13, he-dots) moved into the route dispatch.
// ---------------------------------------------------------------------------
__global__ __launch_bounds__(256) void pre_kernel(
    const float* __restrict__ Ws,
    const float* __restrict__ Wa,
    float* __restrict__ avec,
    int* __restrict__ cnt,
    int* __restrict__ spill_cnt)
{
    int b = blockIdx.x;
    if (b < CNT_BLOCKS) {
        int n = b * 256 + threadIdx.x;
        if (n < N_NODES) cnt[n] = 0;
    } else {
        int t = threadIdx.x;
        if (t < 48) {
            int k = t / IN_DIM;
            int i = t % IN_DIM;
            float acc = 0.f;
            #pragma unroll
            for (int o = 0; o < OUT_DIM; ++o)
                acc += Wa[k * OUT_DIM + o] * Ws[o * IN_DIM + i];
            avec[t] = acc;
        } else if (t == 48) {
            spill_cnt[0] = 0;
        }
    }
}

// ---------------------------------------------------------------------------
// Route (fused): [0,1563) edge blocks, 2 edges/thread phase-split ILP,
// contiguous 512-edge windows (coalesced idx + he stream). Per edge only TWO
// random ops: cnt atomic + 8B entry store. Entry = {(rel<<16)|src, pd}.
// Overflow -> spill list (no hout writes -> hout needs no pre-zero).
// [1563,1759): s1/s3 node dots. [1759,1850): Wrel basis matmul.
// Extras are needed only by reduce; they fill route's idle issue slots
// (route VALUBusy was 1.4%).
// ---------------------------------------------------------------------------
__global__ __launch_bounds__(256) void route_fused_kernel(
    const float* __restrict__ h,
    const float* __restrict__ he,
    const int* __restrict__ src,
    const int* __restrict__ dst,
    const int* __restrict__ rel,
    const float* __restrict__ Ws,
    const float* __restrict__ Wa,
    const float* __restrict__ weight,
    const float* __restrict__ w_comp,
    float* __restrict__ Wrel,
    const float* __restrict__ avec,
    float* __restrict__ s1,
    float* __restrict__ s3,
    int* __restrict__ cnt,
    uint2* __restrict__ bucket,
    int* __restrict__ spill_cnt,
    uint4* __restrict__ spill)
{
    __shared__ float la[48];
    const int b = blockIdx.x;
    const int t = threadIdx.x;

    if (b < EDGE2_BLOCKS) {
        const float4* ap = (const float4*)(avec + 16);
        float4 a0 = ap[0], a1 = ap[1], a2 = ap[2], a3 = ap[3];

        const int base = b * 512;
        const int e0 = base + t;              // always < N_EDGES (max 799999)
        const int e1 = base + 256 + t;
        const bool v1 = (e1 < N_EDGES);
        const int e1c = v1 ? e1 : e0;

        // [1] idx loads (2 independent chains)
        int sA = src[e0], dA = dst[e0], rA = rel[e0];
        int sB = src[e1c], dB = dst[e1c], rB = rel[e1c];

        // [2] he loads + dots (2 independent chains)
        const float4* hepA = (const float4*)(he + (size_t)e0 * IN_DIM);
        const float4* hepB = (const float4*)(he + (size_t)e1c * IN_DIM);
        float4 uA0 = hepA[0], uA1 = hepA[1], uA2 = hepA[2], uA3 = hepA[3];
        float4 uB0 = hepB[0], uB1 = hepB[1], uB2 = hepB[2], uB3 = hepB[3];
        float pdA = uA0.x*a0.x + uA0.y*a0.y + uA0.z*a0.z + uA0.w*a0.w
                  + uA1.x*a1.x + uA1.y*a1.y + uA1.z*a1.z + uA1.w*a1.w
                  + uA2.x*a2.x + uA2.y*a2.y + uA2.z*a2.z + uA2.w*a2.w
                  + uA3.x*a3.x + uA3.y*a3.y + uA3.z*a3.z + uA3.w*a3.w;
        float pdB = uB0.x*a0.x + uB0.y*a0.y + uB0.z*a0.z + uB0.w*a0.w
                  + uB1.x*a1.x + uB1.y*a1.y + uB1.z*a1.z + uB1.w*a1.w
                  + uB2.x*a2.x + uB2.y*a2.y + uB2.z*a2.z + uB2.w*a2.w
                  + uB3.x*a3.x + uB3.y*a3.y + uB3.z*a3.z + uB3.w*a3.w;

        // [3] slot atomics (2 independent)
        int slA = atomicAdd(&cnt[dA], 1);
        int slB = v1 ? atomicAdd(&cnt[dB], 1) : 0;

        // [4] entry stores
        if (slA < CAP) {
            uint2 ent; ent.x = ((unsigned)rA << 16) | (unsigned)sA;
            ent.y = __float_as_uint(pdA);
            bucket[(size_t)dA * CAP + slA] = ent;
        } else {
            int si = atomicAdd(spill_cnt, 1);
            if (si < SPILL_MAX) {
                uint4 sp; sp.x = (unsigned)dA;
                sp.y = ((unsigned)rA << 16) | (unsigned)sA;
                sp.z = __float_as_uint(pdA); sp.w = 0u;
                spill[si] = sp;
            }
        }
        if (v1) {
            if (slB < CAP) {
                uint2 ent; ent.x = ((unsigned)rB << 16) | (unsigned)sB;
                ent.y = __float_as_uint(pdB);
                bucket[(size_t)dB * CAP + slB] = ent;
            } else {
                int si = atomicAdd(spill_cnt, 1);
                if (si < SPILL_MAX) {
                    uint4 sp; sp.x = (unsigned)dB;
                    sp.y = ((unsigned)rB << 16) | (unsigned)sB;
                    sp.z = __float_as_uint(pdB); sp.w = 0u;
                    spill[si] = sp;
                }
            }
        }
    } else if (b < EDGE2_BLOCKS + DOTS_BLOCKS) {
        if (t < 48) {
            int k = t / IN_DIM;
            int i = t % IN_DIM;
            float acc = 0.f;
            #pragma unroll
            for (int o = 0; o < OUT_DIM; ++o)
                acc += Wa[k * OUT_DIM + o] * Ws[o * IN_DIM + i];
            la[t] = acc;
        }
        __syncthreads();
        int n = (b - EDGE2_BLOCKS) * 256 + t;
        if (n >= N_NODES) return;
        const float4* p = (const float4*)(h + (size_t)n * IN_DIM);
        float d1 = 0.f, d3 = 0.f;
        #pragma unroll
        for (int i = 0; i < 4; ++i) {
            float4 v = p[i];
            d1 += v.x * la[4*i+0] + v.y * la[4*i+1] + v.z * la[4*i+2] + v.w * la[4*i+3];
            d3 += v.x * la[32+4*i+0] + v.y * la[32+4*i+1] + v.z * la[32+4*i+2] + v.w * la[32+4*i+3];
        }
        s1[n] = d1;
        s3[n] = d3;
    } else {
        int f = (b - EDGE2_BLOCKS - DOTS_BLOCKS) * 256 + t;
        if (f < N_RELS * IN_DIM * OUT_DIM) {
            int a   = f / (N_RELS * OUT_DIM);
            int rem = f % (N_RELS * OUT_DIM);
            int r   = rem / OUT_DIM;
            int o   = rem % OUT_DIM;
            float acc = 0.f;
            #pragma unroll
            for (int bb = 0; bb < N_BASES; ++bb)
                acc += w_comp[r * N_BASES + bb] * weight[a * (N_BASES * OUT_DIM) + bb * OUT_DIM + o];
            Wrel[f] = acc;
        }
    }
}

// ---------------------------------------------------------------------------
// Reduce+BMM: round-6 datapath verbatim (best measured: 51.5us).
// Persistent 256 blocks (1/CU), 64-node tiles, 16 lanes/node (q = output
// quarter, p = entry stream), 4-entry batch per stream -> 16 entries in
// flight per node. XOR-row addressing for the quad transpose; hq pre-scaled
// by score. Wrel staged in LDS once per block. NEW: spill-list fold for
// deg>CAP nodes (replaces hout pre-zero + atomic overflow), then plain
// full store of every node row.
// ---------------------------------------------------------------------------
__global__ __launch_bounds__(1024) void reduce_bmm_kernel(
    const float* __restrict__ h,
    const float* __restrict__ Wrel,
    const float* __restrict__ s1,
    const float* __restrict__ s3,
    const uint2* __restrict__ bucket,
    const int* __restrict__ cnt,
    const int* __restrict__ spill_cnt,
    const uint4* __restrict__ spill,
    float* __restrict__ hout)
{
    extern __shared__ float lw[];   // [N_RELS * LDS_STRIDE]
    for (int j = threadIdx.x; j < N_RELS * 64; j += 1024) {
        int r = j >> 6;
        int w = j & 63;
        float4 v = ((const float4*)Wrel)[r * 64 + w];
        *(float4*)(lw + r * LDS_STRIDE + w * 4) = v;
    }
    __syncthreads();

    const int l = threadIdx.x & 15;
    const int q = l & 3;
    const int p = l >> 2;               // 0..3: entry stream
    const int gsub = threadIdx.x >> 4;  // node slot within block (0..63)
    const int sn_raw = spill_cnt[0];
    const int sn = sn_raw > SPILL_MAX ? SPILL_MAX : sn_raw;

    for (int n = blockIdx.x * 64 + gsub; n < N_NODES; n += REDUCE_BLOCKS * 64) {
        int deg = cnt[n];
        int m = deg > CAP ? CAP : deg;
        const uint2* ep = bucket + (size_t)n * CAP;
        float s3n = s3[n];
        float4 acc = {0.f, 0.f, 0.f, 0.f};

        for (int j0 = 0; j0 < m; j0 += 16) {
            uint2 ent[4];
            float4 hq[4];
            float s1v[4];
            bool val[4];

            // [1] entry loads (4 q-lanes share addr -> broadcast)
            #pragma unroll
            for (int k = 0; k < 4; ++k) {
                int j = j0 + p * 4 + k;
                val[k] = (j < m);
                ent[k] = ep[val[k] ? j : 0];
            }

            // [2] gathers: h[src] 16B/lane + s1[src] (quad-broadcast);
            //     16 independent chains per node in flight
            #pragma unroll
            for (int k = 0; k < 4; ++k) {
                int sidx = ent[k].x & 0xFFFF;
                hq[k]  = *(const float4*)(h + (size_t)sidx * IN_DIM + q * 4);
                s1v[k] = s1[sidx];
            }

            // [3] process (val[k] uniform across the 4 q-lanes of (n,p))
            #pragma unroll
            for (int k = 0; k < 4; ++k) {
                if (!val[k]) continue;
                unsigned rr = ent[k].x >> 16;
                float score = s1v[k] + s3n + __uint_as_float(ent[k].y);
                float4 hx = hq[k];
                hx.x *= score; hx.y *= score; hx.z *= score; hx.w *= score;

                const float* wb = lw + (size_t)rr * LDS_STRIDE + q * 4;
                #pragma unroll
                for (int mm = 0; mm < 4; ++mm) {
                    float4 vm = (mm == 0) ? hx : shfl_xor4(hx, mm);
                    const float* wrow = wb + (((unsigned)(q ^ mm)) << 6);
                    float4 w0 = *(const float4*)(wrow +  0);
                    float4 w1 = *(const float4*)(wrow + 16);
                    float4 w2 = *(const float4*)(wrow + 32);
                    float4 w3 = *(const float4*)(wrow + 48);
                    acc.x += vm.x*w0.x + vm.y*w1.x + vm.z*w2.x + vm.w*w3.x;
                    acc.y += vm.x*w0.y + vm.y*w1.y + vm.z*w2.y + vm.w*w3.y;
                    acc.z += vm.x*w0.z + vm.y*w1.z + vm.z*w2.z + vm.w*w3.z;
                    acc.w += vm.x*w0.w + vm.y*w1.w + vm.z*w2.w + vm.w*w3.w;
                }
            }
        }

        // spill fold (deg>CAP only; sn is ~always 0). Streams split entries;
        // the d==n test is uniform across the 4 q-lanes of a stream.
        if (deg > CAP) {
            for (int j = p; j < sn; j += 4) {
                uint4 sp = spill[j];
                if ((int)sp.x != n) continue;
                unsigned rr = sp.y >> 16;
                int sidx = sp.y & 0xFFFF;
                float4 hx = *(const float4*)(h + (size_t)sidx * IN_DIM + q * 4);
                float score = s1[sidx] + s3n + __uint_as_float(sp.z);
                hx.x *= score; hx.y *= score; hx.z *= score; hx.w *= score;
                const float* wb = lw + (size_t)rr * LDS_STRIDE + q * 4;
                #pragma unroll
                for (int mm = 0; mm < 4; ++mm) {
                    float4 vm = (mm == 0) ? hx : shfl_xor4(hx, mm);
                    const float* wrow = wb + (((unsigned)(q ^ mm)) << 6);
                    float4 w0 = *(const float4*)(wrow +  0);
                    float4 w1 = *(const float4*)(wrow + 16);
                    float4 w2 = *(const float4*)(wrow + 32);
                    float4 w3 = *(const float4*)(wrow + 48);
                    acc.x += vm.x*w0.x + vm.y*w1.x + vm.z*w2.x + vm.w*w3.x;
                    acc.y += vm.x*w0.y + vm.y*w1.y + vm.z*w2.y + vm.w*w3.y;
                    acc.z += vm.x*w0.z + vm.y*w1.z + vm.z*w2.z + vm.w*w3.z;
                    acc.w += vm.x*w0.w + vm.y*w1.w + vm.z*w2.w + vm.w*w3.w;
                }
            }
        }

        // cross-stream butterfly (within the node's 16 lanes)
        acc.x += __shfl_xor(acc.x, 4); acc.y += __shfl_xor(acc.y, 4);
        acc.z += __shfl_xor(acc.z, 4); acc.w += __shfl_xor(acc.w, 4);
        acc.x += __shfl_xor(acc.x, 8); acc.y += __shfl_xor(acc.y, 8);
        acc.z += __shfl_xor(acc.z, 8); acc.w += __shfl_xor(acc.w, 8);

        // plain full store: every node row fully written here (no pre-zero)
        if (p == 0) {
            *(float4*)(hout + (size_t)n * OUT_DIM + q * 4) = acc;
        }
    }
}

// ===========================================================================
// Fallback (ws too small): direct atomic scatter (known-correct).
// ===========================================================================
__global__ __launch_bounds__(256) void prep_kernel(
    const float* __restrict__ Ws, const float* __restrict__ Wa,
    const float* __restrict__ weight, const float* __restrict__ w_comp,
    float* __restrict__ Wrel, float* __restrict__ avec)
{
    int f = blockIdx.x * blockDim.x + threadIdx.x;
    if (f < N_RELS * IN_DIM * OUT_DIM) {
        int a   = f / (N_RELS * OUT_DIM);
        int rem = f % (N_RELS * OUT_DIM);
        int r   = rem / OUT_DIM;
        int o   = rem % OUT_DIM;
        float acc = 0.f;
        #pragma unroll
        for (int b = 0; b < N_BASES; ++b)
            acc += w_comp[r * N_BASES + b] * weight[a * (N_BASES * OUT_DIM) + b * OUT_DIM + o];
        Wrel[f] = acc;
    } else if (f < N_RELS * IN_DIM * OUT_DIM + 48) {
        int g = f - N_RELS * IN_DIM * OUT_DIM;
        int k = g / IN_DIM;
        int i = g % IN_DIM;
        float acc = 0.f;
        #pragma unroll
        for (int o = 0; o < OUT_DIM; ++o)
            acc += Wa[k * OUT_DIM + o] * Ws[o * IN_DIM + i];
        avec[g] = acc;
    }
}

__global__ __launch_bounds__(256) void edge_atomic_kernel(
    const float* __restrict__ h,
    const float* __restrict__ he,
    const int* __restrict__ src,
    const int* __restrict__ dst,
    const int* __restrict__ rel,
    const float* __restrict__ Wrel,
    const float* __restrict__ avec,
    float* __restrict__ hout)
{
    int e = blockIdx.x * blockDim.x + threadIdx.x;
    if (e >= N_EDGES) return;
    int s = src[e], d = dst[e], r = rel[e];
    float hs[IN_DIM];
    const float4* p = (const float4*)(h + (size_t)s * IN_DIM);
    #pragma unroll
    for (int i = 0; i < 4; ++i) {
        float4 v = p[i];
        hs[4*i+0] = v.x; hs[4*i+1] = v.y; hs[4*i+2] = v.z; hs[4*i+3] = v.w;
    }
    float score = 0.f;
    #pragma unroll
    for (int i = 0; i < IN_DIM; ++i) score += hs[i] * avec[i];
    const float4* qe = (const float4*)(he + (size_t)e * IN_DIM);
    #pragma unroll
    for (int i = 0; i < 4; ++i) {
        float4 v = qe[i];
        score += v.x * avec[16+4*i] + v.y * avec[17+4*i] + v.z * avec[18+4*i] + v.w * avec[19+4*i];
    }
    const float4* pd = (const float4*)(h + (size_t)d * IN_DIM);
    #pragma unroll
    for (int i = 0; i < 4; ++i) {
        float4 v = pd[i];
        score += v.x * avec[32+4*i] + v.y * avec[33+4*i] + v.z * avec[34+4*i] + v.w * avec[35+4*i];
    }
    float acc[OUT_DIM];
    #pragma unroll
    for (int o = 0; o < OUT_DIM; ++o) acc[o] = 0.f;
    const float* W = Wrel + (size_t)r * 256;
    #pragma unroll
    for (int i = 0; i < IN_DIM; ++i) {
        float hv = hs[i];
        #pragma unroll
        for (int o = 0; o < OUT_DIM; ++o) acc[o] += hv * W[i * OUT_DIM + o];
    }
    float* outp = hout + (size_t)d * OUT_DIM;
    #pragma unroll
    for (int o = 0; o < OUT_DIM; ++o) atomicAdd(outp + o, acc[o] * score);
}

extern "C" void kernel_launch(void* const* d_in, const int* in_sizes, int n_in,
                              void* d_out, int out_size, void* d_ws, size_t ws_size,
                              hipStream_t stream) {
    const float* h      = (const float*)d_in[0];
    const float* he     = (const float*)d_in[1];
    const float* Ws     = (const float*)d_in[2];
    const float* Wa     = (const float*)d_in[3];
    const float* weight = (const float*)d_in[4];
    const float* w_comp = (const float*)d_in[5];
    const int*   src    = (const int*)d_in[6];
    const int*   dst    = (const int*)d_in[7];
    const int*   rel    = (const int*)d_in[8];
    float* hout = (float*)d_out;

    // ws layout (float offsets)
    const size_t OFF_WREL     = 0;         // 23040 f
    const size_t OFF_AVEC     = 23040;     // 48 f (+16 pad)
    const size_t OFF_S1       = 23104;     // 50000 f
    const size_t OFF_S3       = 73104;     // 50000 f
    const size_t OFF_CNT      = 123104;    // 50000 i
    const size_t OFF_SPILLCNT = 173104;    // 1 i (+15 pad, keep 16B align)
    const size_t OFF_SPILL    = 173120;    // SPILL_MAX * 4 f (uint4)
    const size_t OFF_BUCKET   = 189504;    // N*CAP uint2
    const size_t NEED_BUCKET = OFF_BUCKET * 4 + (size_t)N_NODES * CAP * sizeof(uint2);

    float* wsf  = (float*)d_ws;
    float* Wrel = wsf + OFF_WREL;
    float* avec = wsf + OFF_AVEC;
    float* s1   = wsf + OFF_S1;
    float* s3   = wsf + OFF_S3;
    int* cnt    = (int*)(wsf + OFF_CNT);
    int* spill_cnt = (int*)(wsf + OFF_SPILLCNT);
    uint4* spill   = (uint4*)(wsf + OFF_SPILL);

    if (ws_size >= NEED_BUCKET) {
        uint2* bucket = (uint2*)(wsf + OFF_BUCKET);

        pre_kernel<<<CNT_BLOCKS + 1, 256, 0, stream>>>(
            Ws, Wa, avec, cnt, spill_cnt);
        route_fused_kernel<<<EDGE2_BLOCKS + DOTS_BLOCKS + WPREP_BLOCKS, 256, 0, stream>>>(
            h, he, src, dst, rel, Ws, Wa, weight, w_comp,
            Wrel, avec, s1, s3, cnt, bucket, spill_cnt, spill);
        reduce_bmm_kernel<<<REDUCE_BLOCKS, 1024,
                            N_RELS * LDS_STRIDE * sizeof(float), stream>>>(
            h, Wrel, s1, s3, bucket, cnt, spill_cnt, spill, hout);
    } else {
        hipMemsetAsync(d_out, 0, (size_t)out_size * sizeof(float), stream);
        int total = N_RELS * IN_DIM * OUT_DIM + 48;
        prep_kernel<<<(total + 255) / 256, 256, 0, stream>>>(Ws, Wa, weight, w_comp, Wrel, avec);
        edge_atomic_kernel<<<(N_EDGES + 255) / 256, 256, 0, stream>>>(
            h, he, src, dst, rel, Wrel, avec, hout);
    }
}